// Round 13
// baseline (48.841 us; speedup 1.0000x reference)
//
#include <hip/hip_runtime.h>

#define NUM_BINS 256
#define PLANES 48                     // B*C = 16*3
#define PLANE_ELEMS (512 * 512)       // H*W
#define BPP 16                        // chunks per plane per input -> 1536 blocks (6/CU)
#define THREADS 256                   // 4 waves
#define F4_PER_BLOCK (PLANE_ELEMS / 4 / BPP)   // 4096 float4
#define F4_PER_THREAD (F4_PER_BLOCK / THREADS) // 16 -> 64 elems/thread
#define NSUB 8                        // sub-histograms (atomic blocks)
#define HSTRIDE 257                   // +1 pad
#define BATCH 4                       // float4 per prefetch batch

__global__ __launch_bounds__(THREADS) void hist_kernel(const float* __restrict__ pred,
                                                       const float* __restrict__ target,
                                                       unsigned* __restrict__ part,
                                                       unsigned* __restrict__ counter) {
    __shared__ alignas(16) unsigned lh[NSUB * HSTRIDE];   // atomic: sub-hists; ballot: stage[4][256]
    const int t = threadIdx.x;
    const int lane = t & 63;
    const int w = t >> 6;
    const int gid = blockIdx.x;

    if (gid == 0 && t == 0) *counter = 0u;   // reset for reduce_kernel (stream-ordered)

    const int which = gid / (PLANES * BPP);
    const int rem   = gid - which * (PLANES * BPP);
    const int plane = rem / BPP;
    const int cblk  = rem - plane * BPP;

    const float* src = which ? target : pred;
    const float4* p = reinterpret_cast<const float4*>(src + (size_t)plane * PLANE_ELEMS)
                      + (size_t)cblk * F4_PER_BLOCK;

    // method selection decoupled from XCD id (XCD = gid & 7): mix within each XCD.
    // 9/16 ballot (VALU pipe), 7/16 atomic (DS pipe) -- both sized under the HBM floor.
    const bool ballot_blk = (((gid >> 3) & 15) < 9);

    if (!ballot_blk) {
        // ================= LDS-atomic block (R10-proven structure) =================
        uint4* l4 = reinterpret_cast<uint4*>(lh);
        for (int i = t; i < (NSUB * HSTRIDE + 3) / 4; i += THREADS) l4[i] = make_uint4(0, 0, 0, 0);
        __syncthreads();

        unsigned* sub = lh + (size_t)(lane & (NSUB - 1)) * HSTRIDE;   // 8 lanes/sub-hist

        float4 cur[BATCH], nxt[BATCH];
#pragma unroll
        for (int j = 0; j < BATCH; ++j) cur[j] = p[j * THREADS + t];

        for (int c = 0; c < F4_PER_THREAD / BATCH; ++c) {
            if (c + 1 < F4_PER_THREAD / BATCH) {
#pragma unroll
                for (int j = 0; j < BATCH; ++j)
                    nxt[j] = p[(c + 1) * BATCH * THREADS + j * THREADS + t];
            }
#pragma unroll
            for (int j = 0; j < BATCH; ++j) {
                float e[4] = {cur[j].x, cur[j].y, cur[j].z, cur[j].w};
#pragma unroll
                for (int k = 0; k < 4; ++k) {
                    int b = (int)(e[k] * 256.0f);   // inputs in [0,1]: trunc == floor
                    b = b > 255 ? 255 : b;          // 1.0 -> last bin
                    atomicAdd(&sub[b], 1u);         // ds_add_u32, no return
                }
            }
#pragma unroll
            for (int j = 0; j < BATCH; ++j) cur[j] = nxt[j];
        }
        __syncthreads();

        unsigned c = 0;
#pragma unroll
        for (int h = 0; h < NSUB; ++h) c += lh[h * HSTRIDE + t];
        part[(size_t)gid * NUM_BINS + t] = c;
    } else {
        // ================= ballot block (pure VALU, no LDS atomics) =================
        const unsigned m0 = ((lane >> 0) & 1) ? 0u : ~0u;
        const unsigned m1 = ((lane >> 1) & 1) ? 0u : ~0u;
        const unsigned m2 = ((lane >> 2) & 1) ? 0u : ~0u;
        const unsigned m3 = ((lane >> 3) & 1) ? 0u : ~0u;
        const unsigned m4 = ((lane >> 4) & 1) ? 0u : ~0u;
        const unsigned m5 = ((lane >> 5) & 1) ? 0u : ~0u;
        unsigned c0 = 0, c1 = 0, c2 = 0, c3 = 0;   // bins {2L, 2L+1, 128+2L, 129+2L}

#define ROUND(xx)                                                                 \
    do {                                                                          \
        float x = (xx);                                                           \
        int b = (int)(x * 256.0f);                                                \
        b = b > 255 ? 255 : b;                                                    \
        unsigned long long B1 = __ballot(b & 2);                                  \
        unsigned long long B2 = __ballot(b & 4);                                  \
        unsigned long long B3 = __ballot(b & 8);                                  \
        unsigned long long B4 = __ballot(b & 16);                                 \
        unsigned long long B5 = __ballot(b & 32);                                 \
        unsigned long long B6 = __ballot(b & 64);                                 \
        unsigned long long B0 = __ballot(b & 1);                                  \
        unsigned long long B7 = __ballot(b & 128);                                \
        unsigned long long Te0 = ~B0 & ~B7, Te1 = B0 & ~B7;                       \
        unsigned long long Te2 = ~B0 &  B7, Te3 = B0 &  B7;                       \
        unsigned lo = ((unsigned)B1 ^ m0) & ((unsigned)B2 ^ m1) &                 \
                      ((unsigned)B3 ^ m2) & ((unsigned)B4 ^ m3) &                 \
                      ((unsigned)B5 ^ m4) & ((unsigned)B6 ^ m5);                  \
        unsigned hi = ((unsigned)(B1 >> 32) ^ m0) & ((unsigned)(B2 >> 32) ^ m1) & \
                      ((unsigned)(B3 >> 32) ^ m2) & ((unsigned)(B4 >> 32) ^ m3) & \
                      ((unsigned)(B5 >> 32) ^ m4) & ((unsigned)(B6 >> 32) ^ m5);  \
        c0 += __popc(lo & (unsigned)Te0) + __popc(hi & (unsigned)(Te0 >> 32));    \
        c1 += __popc(lo & (unsigned)Te1) + __popc(hi & (unsigned)(Te1 >> 32));    \
        c2 += __popc(lo & (unsigned)Te2) + __popc(hi & (unsigned)(Te2 >> 32));    \
        c3 += __popc(lo & (unsigned)Te3) + __popc(hi & (unsigned)(Te3 >> 32));    \
    } while (0)

        float4 cur[BATCH], nxt[BATCH];
#pragma unroll
        for (int j = 0; j < BATCH; ++j) cur[j] = p[j * THREADS + t];

        for (int c = 0; c < F4_PER_THREAD / BATCH; ++c) {
            if (c + 1 < F4_PER_THREAD / BATCH) {
#pragma unroll
                for (int j = 0; j < BATCH; ++j)
                    nxt[j] = p[(c + 1) * BATCH * THREADS + j * THREADS + t];
            }
#pragma unroll
            for (int j = 0; j < BATCH; ++j) {
                ROUND(cur[j].x); ROUND(cur[j].y); ROUND(cur[j].z); ROUND(cur[j].w);
            }
#pragma unroll
            for (int j = 0; j < BATCH; ++j) cur[j] = nxt[j];
        }
#undef ROUND

        // each wave covers all 256 bins: disjoint stage rows, u64 LDS stores, no atomics
        unsigned long long* st64 = reinterpret_cast<unsigned long long*>(lh + w * NUM_BINS);
        st64[lane]      = (unsigned long long)c0 | ((unsigned long long)c1 << 32);
        st64[64 + lane] = (unsigned long long)c2 | ((unsigned long long)c3 << 32);
        __syncthreads();

        unsigned c = lh[0 * NUM_BINS + t] + lh[1 * NUM_BINS + t]
                   + lh[2 * NUM_BINS + t] + lh[3 * NUM_BINS + t];
        part[(size_t)gid * NUM_BINS + t] = c;
    }
}

// one block per plane: merge partials, per-plane sum of d^2; LAST block folds planes -> out
__global__ __launch_bounds__(THREADS) void reduce_kernel(const unsigned* __restrict__ part,
                                                         double* __restrict__ plane_loss,
                                                         unsigned* __restrict__ counter,
                                                         float* __restrict__ out) {
    __shared__ unsigned wa[4], wb[4];
    __shared__ double sd[THREADS];
    __shared__ unsigned sh_old;
    const int t = threadIdx.x;
    const int p = blockIdx.x;

    const unsigned* bp = part + (size_t)p * BPP * NUM_BINS;
    const unsigned* bt = part + (size_t)(PLANES + p) * BPP * NUM_BINS;
    unsigned hp = 0, ht = 0;
#pragma unroll
    for (int j = 0; j < BPP; ++j) {
        hp += bp[j * NUM_BINS + t];
        ht += bt[j * NUM_BINS + t];
    }

    unsigned a = hp, b = ht;
    for (int off = 32; off; off >>= 1) {
        a += __shfl_down(a, off, 64);
        b += __shfl_down(b, off, 64);
    }
    if ((t & 63) == 0) { wa[t >> 6] = a; wb[t >> 6] = b; }
    __syncthreads();
    const unsigned Sp = wa[0] + wa[1] + wa[2] + wa[3];
    const unsigned St = wb[0] + wb[1] + wb[2] + wb[3];

    const double ip = 1.0 / ((double)Sp + 1e-8);
    const double it = 1.0 / ((double)St + 1e-8);
    const double d = (double)hp * ip - (double)ht * it;
    sd[t] = d * d;
    __syncthreads();
    for (int off = THREADS / 2; off; off >>= 1) {   // fixed-order tree: deterministic
        if (t < off) sd[t] += sd[t + off];
        __syncthreads();
    }

    if (t == 0) {
        plane_loss[p] = sd[0];
        __threadfence();                     // release plane_loss[p]
        sh_old = atomicAdd(counter, 1u);     // device-scope
    }
    __syncthreads();

    if (sh_old == PLANES - 1) {              // last block folds all planes (fixed order)
        __threadfence();                     // acquire other blocks' plane_loss
        if (t < 64) {
            double v = (t < PLANES) ? plane_loss[t] : 0.0;
            for (int off = 32; off; off >>= 1) v += __shfl_down(v, off, 64);
            if (t == 0) out[0] = (float)(v / (double)(PLANES * NUM_BINS));
        }
    }
}

extern "C" void kernel_launch(void* const* d_in, const int* in_sizes, int n_in,
                              void* d_out, int out_size, void* d_ws, size_t ws_size,
                              hipStream_t stream) {
    const float* pred   = (const float*)d_in[0];
    const float* target = (const float*)d_in[1];
    float* out = (float*)d_out;
    unsigned* part = (unsigned*)d_ws;                              // [1536][256] u32 = 1.57 MB
    double* plane_loss = reinterpret_cast<double*>(
        (char*)d_ws + (size_t)2 * PLANES * BPP * NUM_BINS * sizeof(unsigned));  // [48] f64
    unsigned* counter = reinterpret_cast<unsigned*>(plane_loss + PLANES);       // [1] u32

    hist_kernel<<<2 * PLANES * BPP, THREADS, 0, stream>>>(pred, target, part, counter);
    reduce_kernel<<<PLANES, THREADS, 0, stream>>>(part, plane_loss, counter, out);
}

// Round 14
// 26.453 us; speedup vs baseline: 1.8464x; 1.8464x over previous
//
#include <hip/hip_runtime.h>

#define NUM_BINS 256
#define PLANES 48                     // B*C = 16*3
#define PLANE_ELEMS (512 * 512)       // H*W
#define BPP 16                        // chunks per plane per input -> 1536 blocks (6/CU)
#define THREADS 256                   // 4 waves, all LDS-atomic
#define F4_PER_BLOCK (PLANE_ELEMS / 4 / BPP)   // 4096 float4
#define F4_PER_THREAD (F4_PER_BLOCK / THREADS) // 16 -> 64 elems/thread
#define NSUB 8                        // sub-histograms shared by the whole block
#define HSTRIDE 257                   // +1 pad
#define BATCH 4                       // float4 per prefetch batch

__global__ __launch_bounds__(THREADS) void hist_kernel(const float* __restrict__ pred,
                                                       const float* __restrict__ target,
                                                       unsigned* __restrict__ part,
                                                       unsigned* __restrict__ counter) {
    __shared__ alignas(16) unsigned lh[NSUB * HSTRIDE];
    const int t = threadIdx.x;
    const int lane = t & 63;
    const int gid = blockIdx.x;

    if (gid == 0 && t == 0) *counter = 0u;   // reset for reduce_kernel (stream-ordered)

    // zero sub-hists with wide LDS writes (2056 words = 514 uint4)
    uint4* l4 = reinterpret_cast<uint4*>(lh);
    for (int i = t; i < (NSUB * HSTRIDE + 3) / 4; i += THREADS) l4[i] = make_uint4(0, 0, 0, 0);
    __syncthreads();

    const int which = gid / (PLANES * BPP);
    const int rem   = gid - which * (PLANES * BPP);
    const int plane = rem / BPP;
    const int cblk  = rem - plane * BPP;

    const float* src = which ? target : pred;
    const float4* p = reinterpret_cast<const float4*>(src + (size_t)plane * PLANE_ELEMS)
                      + (size_t)cblk * F4_PER_BLOCK;

    // each lane uses sub-hist (lane & 7): 8 lanes/sub-hist per wave-op
    unsigned* sub = lh + (size_t)(lane & (NSUB - 1)) * HSTRIDE;

    // double-buffered register prefetch: BATCH float4 in flight while binning
    float4 cur[BATCH], nxt[BATCH];
#pragma unroll
    for (int j = 0; j < BATCH; ++j) cur[j] = p[j * THREADS + t];

    for (int c = 0; c < F4_PER_THREAD / BATCH; ++c) {
        if (c + 1 < F4_PER_THREAD / BATCH) {
#pragma unroll
            for (int j = 0; j < BATCH; ++j)
                nxt[j] = p[(c + 1) * BATCH * THREADS + j * THREADS + t];
        }
#pragma unroll
        for (int j = 0; j < BATCH; ++j) {
            float e[4] = {cur[j].x, cur[j].y, cur[j].z, cur[j].w};
#pragma unroll
            for (int k = 0; k < 4; ++k) {
                int b = (int)(e[k] * 256.0f);   // inputs in [0,1]: trunc == floor
                b = b > 255 ? 255 : b;          // 1.0 -> last bin
                atomicAdd(&sub[b], 1u);         // ds_add_u32, no return
            }
        }
#pragma unroll
        for (int j = 0; j < BATCH; ++j) cur[j] = nxt[j];
    }
    __syncthreads();

    // flush: thread t owns bin t — 8 LDS reads + ONE coalesced plain store
    unsigned c = 0;
#pragma unroll
    for (int h = 0; h < NSUB; ++h) c += lh[h * HSTRIDE + t];
    part[(size_t)gid * NUM_BINS + t] = c;       // every slot overwritten every call
}

// one block per plane: merge partials, per-plane sum of d^2; LAST block folds planes -> out
__global__ __launch_bounds__(THREADS) void reduce_kernel(const unsigned* __restrict__ part,
                                                         double* __restrict__ plane_loss,
                                                         unsigned* __restrict__ counter,
                                                         float* __restrict__ out) {
    __shared__ unsigned wa[4], wb[4];
    __shared__ double sd[THREADS];
    __shared__ unsigned sh_old;
    const int t = threadIdx.x;
    const int p = blockIdx.x;

    const unsigned* bp = part + (size_t)p * BPP * NUM_BINS;
    const unsigned* bt = part + (size_t)(PLANES + p) * BPP * NUM_BINS;
    unsigned hp = 0, ht = 0;
#pragma unroll
    for (int j = 0; j < BPP; ++j) {
        hp += bp[j * NUM_BINS + t];
        ht += bt[j * NUM_BINS + t];
    }

    // exact integer plane totals
    unsigned a = hp, b = ht;
    for (int off = 32; off; off >>= 1) {
        a += __shfl_down(a, off, 64);
        b += __shfl_down(b, off, 64);
    }
    if ((t & 63) == 0) { wa[t >> 6] = a; wb[t >> 6] = b; }
    __syncthreads();
    const unsigned Sp = wa[0] + wa[1] + wa[2] + wa[3];
    const unsigned St = wb[0] + wb[1] + wb[2] + wb[3];

    const double ip = 1.0 / ((double)Sp + 1e-8);
    const double it = 1.0 / ((double)St + 1e-8);
    const double d = (double)hp * ip - (double)ht * it;
    sd[t] = d * d;
    __syncthreads();
    for (int off = THREADS / 2; off; off >>= 1) {   // fixed-order tree: deterministic
        if (t < off) sd[t] += sd[t + off];
        __syncthreads();
    }

    if (t == 0) {
        plane_loss[p] = sd[0];
        __threadfence();                     // release plane_loss[p]
        sh_old = atomicAdd(counter, 1u);     // device-scope
    }
    __syncthreads();

    if (sh_old == PLANES - 1) {              // last block folds all planes (fixed order)
        __threadfence();                     // acquire other blocks' plane_loss
        if (t < 64) {
            double v = (t < PLANES) ? plane_loss[t] : 0.0;
            for (int off = 32; off; off >>= 1) v += __shfl_down(v, off, 64);
            if (t == 0) out[0] = (float)(v / (double)(PLANES * NUM_BINS));
        }
    }
}

extern "C" void kernel_launch(void* const* d_in, const int* in_sizes, int n_in,
                              void* d_out, int out_size, void* d_ws, size_t ws_size,
                              hipStream_t stream) {
    const float* pred   = (const float*)d_in[0];
    const float* target = (const float*)d_in[1];
    float* out = (float*)d_out;
    unsigned* part = (unsigned*)d_ws;                              // [1536][256] u32 = 1.57 MB
    double* plane_loss = reinterpret_cast<double*>(
        (char*)d_ws + (size_t)2 * PLANES * BPP * NUM_BINS * sizeof(unsigned));  // [48] f64
    unsigned* counter = reinterpret_cast<unsigned*>(plane_loss + PLANES);       // [1] u32

    hist_kernel<<<2 * PLANES * BPP, THREADS, 0, stream>>>(pred, target, part, counter);
    reduce_kernel<<<PLANES, THREADS, 0, stream>>>(part, plane_loss, counter, out);
}

// Round 15
// 24.746 us; speedup vs baseline: 1.9737x; 1.0689x over previous
//
#include <hip/hip_runtime.h>

#define NUM_BINS 256
#define PLANES 48                     // B*C = 16*3
#define PLANE_ELEMS (512 * 512)       // H*W
#define BPP 16                        // chunks per plane per input -> 1536 blocks (6/CU)
#define THREADS 256                   // 4 waves, all LDS-atomic
#define F4_PER_BLOCK (PLANE_ELEMS / 4 / BPP)   // 4096 float4
#define F4_PER_THREAD (F4_PER_BLOCK / THREADS) // 16 -> 64 elems/thread
#define NSUB 8                        // sub-histograms shared by the whole block
#define HSTRIDE 257                   // +1 pad
#define BATCH 4                       // float4 per prefetch batch

__global__ __launch_bounds__(THREADS) void hist_kernel(const float* __restrict__ pred,
                                                       const float* __restrict__ target,
                                                       unsigned* __restrict__ part) {
    __shared__ alignas(16) unsigned lh[NSUB * HSTRIDE];
    const int t = threadIdx.x;
    const int lane = t & 63;

    // zero sub-hists with wide LDS writes
    uint4* l4 = reinterpret_cast<uint4*>(lh);
    for (int i = t; i < (NSUB * HSTRIDE + 3) / 4; i += THREADS) l4[i] = make_uint4(0, 0, 0, 0);
    __syncthreads();

    const int gid   = blockIdx.x;
    const int which = gid / (PLANES * BPP);
    const int rem   = gid - which * (PLANES * BPP);
    const int plane = rem / BPP;
    const int cblk  = rem - plane * BPP;

    const float* src = which ? target : pred;
    const float4* p = reinterpret_cast<const float4*>(src + (size_t)plane * PLANE_ELEMS)
                      + (size_t)cblk * F4_PER_BLOCK;

    // each lane uses sub-hist (lane & 7): 8 lanes/sub-hist per wave-op
    unsigned* sub = lh + (size_t)(lane & (NSUB - 1)) * HSTRIDE;

    // double-buffered register prefetch: BATCH float4 in flight while binning
    float4 cur[BATCH], nxt[BATCH];
#pragma unroll
    for (int j = 0; j < BATCH; ++j) cur[j] = p[j * THREADS + t];

    for (int c = 0; c < F4_PER_THREAD / BATCH; ++c) {
        if (c + 1 < F4_PER_THREAD / BATCH) {
#pragma unroll
            for (int j = 0; j < BATCH; ++j)
                nxt[j] = p[(c + 1) * BATCH * THREADS + j * THREADS + t];
        }
#pragma unroll
        for (int j = 0; j < BATCH; ++j) {
            float e[4] = {cur[j].x, cur[j].y, cur[j].z, cur[j].w};
#pragma unroll
            for (int k = 0; k < 4; ++k) {
                int b = (int)(e[k] * 256.0f);   // inputs in [0,1]: trunc == floor
                b = b > 255 ? 255 : b;          // 1.0 -> last bin
                atomicAdd(&sub[b], 1u);         // ds_add_u32, no return
            }
        }
#pragma unroll
        for (int j = 0; j < BATCH; ++j) cur[j] = nxt[j];
    }
    __syncthreads();

    // flush: thread t owns bin t — 8 LDS reads + ONE coalesced plain store
    unsigned c = 0;
#pragma unroll
    for (int h = 0; h < NSUB; ++h) c += lh[h * HSTRIDE + t];
    part[(size_t)gid * NUM_BINS + t] = c;       // every slot overwritten every call
}

// one block per plane: merge 16+16 partials, normalize, per-plane sum of d^2
__global__ __launch_bounds__(THREADS) void plane_kernel(const unsigned* __restrict__ part,
                                                        double* __restrict__ plane_loss) {
    __shared__ unsigned wa[4], wb[4];
    __shared__ double sd[THREADS];
    const int t = threadIdx.x;
    const int p = blockIdx.x;

    const unsigned* bp = part + (size_t)p * BPP * NUM_BINS;                   // pred partials
    const unsigned* bt = part + (size_t)(PLANES + p) * BPP * NUM_BINS;        // target partials
    unsigned hp = 0, ht = 0;
#pragma unroll
    for (int j = 0; j < BPP; ++j) {
        hp += bp[j * NUM_BINS + t];
        ht += bt[j * NUM_BINS + t];
    }

    // plane totals (exact integer counts)
    unsigned a = hp, b = ht;
    for (int off = 32; off; off >>= 1) {
        a += __shfl_down(a, off, 64);
        b += __shfl_down(b, off, 64);
    }
    if ((t & 63) == 0) { wa[t >> 6] = a; wb[t >> 6] = b; }
    __syncthreads();
    const unsigned Sp = wa[0] + wa[1] + wa[2] + wa[3];
    const unsigned St = wb[0] + wb[1] + wb[2] + wb[3];

    const double ip = 1.0 / ((double)Sp + 1e-8);
    const double it = 1.0 / ((double)St + 1e-8);
    const double d = (double)hp * ip - (double)ht * it;
    sd[t] = d * d;
    __syncthreads();
    for (int off = THREADS / 2; off; off >>= 1) {   // fixed-order tree: deterministic
        if (t < off) sd[t] += sd[t + off];
        __syncthreads();
    }
    if (t == 0) plane_loss[p] = sd[0];
}

__global__ __launch_bounds__(64) void final_kernel(const double* __restrict__ plane_loss,
                                                   float* __restrict__ out) {
    const int t = threadIdx.x;
    double v = (t < PLANES) ? plane_loss[t] : 0.0;
    for (int off = 32; off; off >>= 1) v += __shfl_down(v, off, 64);
    if (t == 0) out[0] = (float)(v / (double)(PLANES * NUM_BINS));
}

extern "C" void kernel_launch(void* const* d_in, const int* in_sizes, int n_in,
                              void* d_out, int out_size, void* d_ws, size_t ws_size,
                              hipStream_t stream) {
    const float* pred   = (const float*)d_in[0];
    const float* target = (const float*)d_in[1];
    float* out = (float*)d_out;
    unsigned* part = (unsigned*)d_ws;                              // [2*48*16][256] u32 = 1.57 MB
    double* plane_loss = reinterpret_cast<double*>(
        (char*)d_ws + (size_t)2 * PLANES * BPP * NUM_BINS * sizeof(unsigned));  // [48] f64

    hist_kernel<<<2 * PLANES * BPP, THREADS, 0, stream>>>(pred, target, part);
    plane_kernel<<<PLANES, THREADS, 0, stream>>>(part, plane_loss);
    final_kernel<<<1, 64, 0, stream>>>(plane_loss, out);
}